// Round 1
// baseline (185.250 us; speedup 1.0000x reference)
//
#include <hip/hip_runtime.h>

#define DIMV 128
#define CDIM 127
static constexpr long long NCELL = 127LL * 127LL * 127LL;          // 2,048,383
static constexpr long long VTX_FLOATS = NCELL * 45;                // 92,177,235
static constexpr long long CNT_OFF = NCELL * 50;                   // 102,419,150

#define P1  -1
#define P4  -1,-1,-1,-1
#define P7  -1,-1,-1,-1,-1,-1,-1
#define P10 -1,-1,-1,-1,-1,-1,-1,-1,-1,-1
#define P13 -1,-1,-1,-1,-1,-1,-1,-1,-1,-1,-1,-1,-1
#define P16 -1,-1,-1,-1,-1,-1,-1,-1,-1,-1,-1,-1,-1,-1,-1,-1

__device__ const signed char TRI_TBL[256][16] = {
{P16},
{0,8,3,P13},
{0,1,9,P13},
{1,8,3,9,8,1,P10},
{1,2,10,P13},
{0,8,3,1,2,10,P10},
{9,2,10,0,2,9,P10},
{2,8,3,2,10,8,10,9,8,P7},
{3,11,2,P13},
{0,11,2,8,11,0,P10},
{1,9,0,2,3,11,P10},
{1,11,2,1,9,11,9,8,11,P7},
{3,10,1,11,10,3,P10},
{0,10,1,0,8,10,8,11,10,P7},
{3,9,0,3,11,9,11,10,9,P7},
{9,8,10,10,8,11,P10},
{4,7,8,P13},
{4,3,0,7,3,4,P10},
{0,1,9,8,4,7,P10},
{4,1,9,4,7,1,7,3,1,P7},
{1,2,10,8,4,7,P10},
{3,4,7,3,0,4,1,2,10,P7},
{9,2,10,9,0,2,8,4,7,P7},
{2,10,9,2,9,7,2,7,3,7,9,4,P4},
{8,4,7,3,11,2,P10},
{11,4,7,11,2,4,2,0,4,P7},
{9,0,1,8,4,7,2,3,11,P7},
{4,7,11,9,4,11,9,11,2,9,2,1,P4},
{3,10,1,3,11,10,7,8,4,P7},
{1,11,10,1,4,11,1,0,4,7,11,4,P4},
{4,7,8,9,0,11,9,11,10,11,0,3,P4},
{4,7,11,4,11,9,9,11,10,P7},
{9,5,4,P13},
{9,5,4,0,8,3,P10},
{0,5,4,1,5,0,P10},
{8,5,4,8,3,5,3,1,5,P7},
{1,2,10,9,5,4,P10},
{3,0,8,1,2,10,4,9,5,P7},
{5,2,10,5,4,2,4,0,2,P7},
{2,10,5,3,2,5,3,5,4,3,4,8,P4},
{9,5,4,2,3,11,P10},
{0,11,2,0,8,11,4,9,5,P7},
{0,5,4,0,1,5,2,3,11,P7},
{2,1,5,2,5,8,2,8,11,4,8,5,P4},
{10,3,11,10,1,3,9,5,4,P7},
{4,9,5,0,8,1,8,10,1,8,11,10,P4},
{5,4,0,5,0,11,5,11,10,11,0,3,P4},
{5,4,8,5,8,10,10,8,11,P7},
{9,7,8,5,7,9,P10},
{9,3,0,9,5,3,5,7,3,P7},
{0,7,8,0,1,7,1,5,7,P7},
{1,5,3,3,5,7,P10},
{9,7,8,9,5,7,10,1,2,P7},
{10,1,2,9,5,0,5,3,0,5,7,3,P4},
{8,0,2,8,2,5,8,5,7,10,5,2,P4},
{2,10,5,2,5,3,3,5,7,P7},
{7,9,5,7,8,9,3,11,2,P7},
{9,5,7,9,7,2,9,2,0,2,7,11,P4},
{2,3,11,0,1,8,1,7,8,1,5,7,P4},
{11,2,1,11,1,7,7,1,5,P7},
{9,5,8,8,5,7,10,1,3,10,3,11,P4},
{5,7,0,5,0,9,7,11,0,1,0,10,11,10,0,P1},
{11,10,0,11,0,3,10,5,0,8,0,7,5,7,0,P1},
{11,10,5,7,11,5,P10},
{10,6,5,P13},
{0,8,3,5,10,6,P10},
{9,0,1,5,10,6,P10},
{1,8,3,1,9,8,5,10,6,P7},
{1,6,5,2,6,1,P10},
{1,6,5,1,2,6,3,0,8,P7},
{9,6,5,9,0,6,0,2,6,P7},
{5,9,8,5,8,2,5,2,6,3,2,8,P4},
{2,3,11,10,6,5,P10},
{11,0,8,11,2,0,10,6,5,P7},
{0,1,9,2,3,11,5,10,6,P7},
{5,10,6,1,9,2,9,11,2,9,8,11,P4},
{6,3,11,6,5,3,5,1,3,P7},
{0,8,11,0,11,5,0,5,1,5,11,6,P4},
{3,11,6,0,3,6,0,6,5,0,5,9,P4},
{6,5,9,6,9,11,11,9,8,P7},
{5,10,6,4,7,8,P10},
{4,3,0,4,7,3,6,5,10,P7},
{1,9,0,5,10,6,8,4,7,P7},
{10,6,5,1,9,7,1,7,3,7,9,4,P4},
{6,1,2,6,5,1,4,7,8,P7},
{1,2,5,5,2,6,3,0,4,3,4,7,P4},
{8,4,7,9,0,5,0,6,5,0,2,6,P4},
{7,3,9,7,9,4,3,2,9,5,9,6,2,6,9,P1},
{3,11,2,7,8,4,10,6,5,P7},
{5,10,6,4,7,2,4,2,0,2,7,11,P4},
{0,1,9,4,7,8,2,3,11,5,10,6,P4},
{9,2,1,9,11,2,9,4,11,7,11,4,5,10,6,P1},
{8,4,7,3,11,5,3,5,1,5,11,6,P4},
{5,1,11,5,11,6,1,0,11,7,11,4,0,4,11,P1},
{0,5,9,0,6,5,0,3,6,11,6,3,8,4,7,P1},
{6,5,9,6,9,11,4,7,9,7,11,9,P4},
{10,4,9,6,4,10,P10},
{4,10,6,4,9,10,0,8,3,P7},
{10,0,1,10,6,0,6,4,0,P7},
{8,3,1,8,1,6,8,6,4,6,1,10,P4},
{1,4,9,1,2,4,2,6,4,P7},
{3,0,8,1,2,9,2,4,9,2,6,4,P4},
{0,2,4,4,2,6,P10},
{8,3,2,8,2,4,4,2,6,P7},
{10,4,9,10,6,4,11,2,3,P7},
{0,8,2,2,8,11,4,9,10,4,10,6,P4},
{3,11,2,0,1,6,0,6,4,6,1,10,P4},
{6,4,1,6,1,10,4,8,1,2,1,11,8,11,1,P1},
{9,6,4,9,3,6,9,1,3,11,6,3,P4},
{8,11,1,8,1,0,11,6,1,9,1,4,6,4,1,P1},
{3,11,6,3,6,0,0,6,4,P7},
{6,4,8,11,6,8,P10},
{7,10,6,7,8,10,8,9,10,P7},
{0,7,3,0,10,7,0,9,10,6,7,10,P4},
{10,6,7,1,10,7,1,7,8,1,8,0,P4},
{10,6,7,10,7,1,1,7,3,P7},
{1,2,6,1,6,8,1,8,9,8,6,7,P4},
{2,6,9,2,9,1,6,7,9,0,9,3,7,3,9,P1},
{7,8,0,7,0,6,6,0,2,P7},
{7,3,2,6,7,2,P10},
{2,3,11,10,6,8,10,8,9,8,6,7,P4},
{2,0,7,2,7,11,0,9,7,6,7,10,9,10,7,P1},
{1,8,0,1,7,8,1,10,7,6,7,10,2,3,11,P1},
{11,2,1,11,1,7,10,6,1,6,7,1,P4},
{8,9,6,8,6,7,9,1,6,11,6,3,1,3,6,P1},
{0,9,1,11,6,7,P10},
{7,8,0,7,0,6,3,11,0,11,6,0,P4},
{7,11,6,P13},
{7,6,11,P13},
{3,0,8,11,7,6,P10},
{0,1,9,11,7,6,P10},
{8,1,9,8,3,1,11,7,6,P7},
{10,1,2,6,11,7,P10},
{1,2,10,3,0,8,6,11,7,P7},
{2,9,0,2,10,9,6,11,7,P7},
{6,11,7,2,10,3,10,8,3,10,9,8,P4},
{7,2,3,6,2,7,P10},
{7,0,8,7,6,0,6,2,0,P7},
{2,7,6,2,3,7,0,1,9,P7},
{1,6,2,1,8,6,1,9,8,8,7,6,P4},
{10,7,6,10,1,7,1,3,7,P7},
{10,7,6,1,7,10,1,8,7,1,0,8,P4},
{0,3,7,0,7,10,0,10,9,6,10,7,P4},
{7,6,10,7,10,8,8,10,9,P7},
{6,8,4,11,8,6,P10},
{3,6,11,3,0,6,0,4,6,P7},
{8,6,11,8,4,6,9,0,1,P7},
{9,4,6,9,6,3,9,3,1,11,3,6,P4},
{6,8,4,6,11,8,2,10,1,P7},
{1,2,10,3,0,11,0,6,11,0,4,6,P4},
{4,11,8,4,6,11,0,2,9,2,10,9,P4},
{10,9,3,10,3,2,9,4,3,11,3,6,4,6,3,P1},
{8,2,3,8,4,2,4,6,2,P7},
{0,4,2,4,6,2,P10},
{1,9,0,2,3,4,2,4,6,4,3,8,P4},
{1,9,4,1,4,2,2,4,6,P7},
{8,1,3,8,6,1,8,4,6,6,10,1,P4},
{10,1,0,10,0,6,6,0,4,P7},
{4,6,3,4,3,8,6,10,3,0,3,9,10,9,3,P1},
{10,9,4,6,10,4,P10},
{4,9,5,7,6,11,P10},
{0,8,3,4,9,5,11,7,6,P7},
{5,0,1,5,4,0,7,6,11,P7},
{11,7,6,8,3,4,3,5,4,3,1,5,P4},
{9,5,4,10,1,2,7,6,11,P7},
{6,11,7,1,2,10,0,8,3,4,9,5,P4},
{7,6,11,5,4,10,4,2,10,4,0,2,P4},
{3,4,8,3,5,4,3,2,5,10,5,2,11,7,6,P1},
{7,2,3,7,6,2,5,4,9,P7},
{9,5,4,0,8,6,0,6,2,6,8,7,P4},
{3,6,2,3,7,6,1,5,0,5,4,0,P4},
{6,2,8,6,8,7,2,1,8,4,8,5,1,5,8,P1},
{9,5,4,10,1,6,1,7,6,1,3,7,P4},
{1,6,10,1,7,6,1,0,7,8,7,0,9,5,4,P1},
{4,0,10,4,10,5,0,3,10,6,10,7,3,7,10,P1},
{7,6,10,7,10,8,5,4,10,4,8,10,P4},
{6,9,5,6,11,9,11,8,9,P7},
{3,6,11,0,6,3,0,5,6,0,9,5,P4},
{0,11,8,0,5,11,0,1,5,5,6,11,P4},
{6,11,3,6,3,5,5,3,1,P7},
{1,2,10,9,5,11,9,11,8,11,5,6,P4},
{0,11,3,0,6,11,0,9,6,5,6,9,1,2,10,P1},
{11,8,5,11,5,6,8,0,5,10,5,2,0,2,5,P1},
{6,11,3,6,3,5,2,10,3,10,5,3,P4},
{5,8,9,5,2,8,5,6,2,3,8,2,P4},
{9,5,6,9,6,0,0,6,2,P7},
{1,5,8,1,8,0,5,6,8,3,8,2,6,2,8,P1},
{1,5,6,2,1,6,P10},
{1,3,6,1,6,10,3,8,6,5,6,9,8,9,6,P1},
{10,1,0,10,0,6,9,5,0,5,6,0,P4},
{0,3,8,5,6,10,P10},
{10,5,6,P13},
{11,5,10,7,5,11,P10},
{11,5,10,11,7,5,8,3,0,P7},
{5,11,7,5,10,11,1,9,0,P7},
{10,7,5,10,11,7,9,8,1,8,3,1,P4},
{11,1,2,11,7,1,7,5,1,P7},
{0,8,3,1,2,7,1,7,5,7,2,11,P4},
{9,7,5,9,2,7,9,0,2,2,11,7,P4},
{7,5,2,7,2,11,5,9,2,3,2,8,9,8,2,P1},
{2,5,10,2,3,5,3,7,5,P7},
{8,2,0,8,5,2,8,7,5,10,2,5,P4},
{9,0,1,5,10,3,5,3,7,3,10,2,P4},
{9,8,2,9,2,1,8,7,2,10,2,5,7,5,2,P1},
{1,3,5,3,7,5,P10},
{0,8,7,0,7,1,1,7,5,P7},
{9,0,3,9,3,5,5,3,7,P7},
{9,8,7,5,9,7,P10},
{5,8,4,5,10,8,10,11,8,P7},
{5,0,4,5,11,0,5,10,11,11,3,0,P4},
{0,1,9,8,4,10,8,10,11,10,4,5,P4},
{10,11,4,10,4,5,11,3,4,9,4,1,3,1,4,P1},
{2,5,1,2,8,5,2,11,8,4,5,8,P4},
{0,4,11,0,11,3,4,5,11,2,11,1,5,1,11,P1},
{0,2,5,0,5,9,2,11,5,4,5,8,11,8,5,P1},
{9,4,5,2,11,3,P10},
{2,5,10,3,5,2,3,4,5,3,8,4,P4},
{5,10,2,5,2,4,4,2,0,P7},
{3,10,2,3,5,10,3,8,5,4,5,8,0,1,9,P1},
{5,10,2,5,2,4,1,9,2,9,4,2,P4},
{8,4,5,8,5,3,3,5,1,P7},
{0,4,5,1,0,5,P10},
{8,4,5,8,5,3,9,0,5,0,3,5,P4},
{9,4,5,P13},
{4,11,7,4,9,11,9,10,11,P7},
{0,8,3,4,9,7,9,11,7,9,10,11,P4},
{1,10,11,1,11,4,1,4,0,7,4,11,P4},
{3,1,4,3,4,8,1,10,4,7,4,11,10,11,4,P1},
{4,11,7,9,11,4,9,2,11,9,1,2,P4},
{9,7,4,9,11,7,9,1,11,2,11,1,0,8,3,P1},
{11,7,4,11,4,2,2,4,0,P7},
{11,7,4,11,4,2,8,3,4,3,2,4,P4},
{2,9,10,2,7,9,2,3,7,7,4,9,P4},
{9,10,7,9,7,4,10,2,7,8,7,0,2,0,7,P1},
{3,7,10,3,10,2,7,4,10,1,10,0,4,0,10,P1},
{1,10,2,8,7,4,P10},
{4,9,1,4,1,7,7,1,3,P7},
{4,9,1,4,1,7,0,8,1,8,7,1,P4},
{4,0,3,7,4,3,P10},
{4,8,7,P13},
{9,10,8,10,11,8,P10},
{3,0,9,3,9,11,11,9,10,P7},
{0,1,10,0,10,8,8,10,11,P7},
{3,1,10,11,3,10,P10},
{1,2,11,1,11,9,9,11,8,P7},
{3,0,9,3,9,11,1,2,9,2,11,9,P4},
{0,2,11,8,0,11,P10},
{3,2,11,P13},
{2,3,8,2,8,10,10,8,9,P7},
{9,10,2,0,9,2,P10},
{2,3,8,2,8,10,0,1,8,1,10,8,P4},
{1,10,2,P13},
{1,3,8,9,1,8,P10},
{0,9,1,P13},
{0,3,8,P13},
{P16}
};

__global__ __launch_bounds__(256) void mc_kernel(const float* __restrict__ vol,
                                                 float* __restrict__ out) {
    // Per-thread edge-vertex storage in LDS: [36 rows][256 threads].
    // Lane i's column is bank (i%32) -> 2-way aliasing only (free on CDNA4).
    __shared__ float ev_s[36][256];
    __shared__ int4  tri_s[256];
    __shared__ int   wsum[4];

    const int tid = threadIdx.x;
    tri_s[tid] = ((const int4*)TRI_TBL)[tid];   // 4 KB table -> LDS
    __syncthreads();

    const long long cell = (long long)blockIdx.x * 256 + tid;
    const bool active = cell < NCELL;
    int cnt = 0;

    if (active) {
        const int x = (int)(cell % CDIM);
        const int r = (int)(cell / CDIM);
        const int y = r % CDIM;
        const int z = r / CDIM;

        const float* p = vol + ((size_t)z * DIMV + y) * DIMV + x;
        float cv[8];
        cv[0] = p[0];
        cv[1] = p[1];
        cv[3] = p[DIMV];
        cv[2] = p[DIMV + 1];
        cv[4] = p[DIMV * DIMV];
        cv[5] = p[DIMV * DIMV + 1];
        cv[7] = p[DIMV * DIMV + DIMV];
        cv[6] = p[DIMV * DIMV + DIMV + 1];

        int cidx = 0;
#pragma unroll
        for (int k = 0; k < 8; ++k)
            cidx |= (cv[k] < 0.5f) ? (1 << k) : 0;

        const int   EA[12] = {0,1,2,3,4,5,6,7,0,1,2,3};
        const int   EB[12] = {1,2,3,0,5,6,7,4,4,5,6,7};
        const float OX[8]  = {0,1,1,0,0,1,1,0};
        const float OY[8]  = {0,0,1,1,0,0,1,1};
        const float OZ[8]  = {0,0,0,0,1,1,1,1};

        const float xf = (float)x, yf = (float)y, zf = (float)z;
#pragma unroll
        for (int e = 0; e < 12; ++e) {
            const float v1 = cv[EA[e]];
            const float v2 = cv[EB[e]];
            const float d  = v2 - v1;
            const float t  = (fabsf(d) > 1e-9f) ? ((0.5f - v1) / d) : 0.5f;
            ev_s[3*e + 0][tid] = xf + OX[EA[e]] + t * (OX[EB[e]] - OX[EA[e]]);
            ev_s[3*e + 1][tid] = yf + OY[EA[e]] + t * (OY[EB[e]] - OY[EA[e]]);
            ev_s[3*e + 2][tid] = zf + OZ[EA[e]] + t * (OZ[EB[e]] - OZ[EA[e]]);
        }

        const int4 row = tri_s[cidx];
        const int  rw[4] = {row.x, row.y, row.z, row.w};

        const size_t vb  = (size_t)cell * 45;
        const size_t tvb = (size_t)VTX_FLOATS + (size_t)cell * 5;

#pragma unroll
        for (int t5 = 0; t5 < 5; ++t5) {
            const int b0 = 3*t5, b1 = 3*t5 + 1, b2 = 3*t5 + 2;
            const int e0 = (int)(signed char)((rw[b0 >> 2] >> ((b0 & 3) * 8)) & 0xFF);
            const int e1 = (int)(signed char)((rw[b1 >> 2] >> ((b1 & 3) * 8)) & 0xFF);
            const int e2 = (int)(signed char)((rw[b2 >> 2] >> ((b2 & 3) * 8)) & 0xFF);
            const bool val = (e0 >= 0);
            const float mm = val ? 1.0f : 0.0f;
            const int j0 = val ? e0 : 0;
            const int j1 = val ? e1 : 0;
            const int j2 = val ? e2 : 0;

            float* o = out + vb + 9 * t5;
            o[0] = ev_s[3*j0 + 0][tid] * mm;
            o[1] = ev_s[3*j0 + 1][tid] * mm;
            o[2] = ev_s[3*j0 + 2][tid] * mm;
            o[3] = ev_s[3*j1 + 0][tid] * mm;
            o[4] = ev_s[3*j1 + 1][tid] * mm;
            o[5] = ev_s[3*j1 + 2][tid] * mm;
            o[6] = ev_s[3*j2 + 0][tid] * mm;
            o[7] = ev_s[3*j2 + 1][tid] * mm;
            o[8] = ev_s[3*j2 + 2][tid] * mm;

            out[tvb + t5] = mm;
            cnt += val ? 1 : 0;
        }
    }

    // Block-level count reduction -> one float atomic per block.
#pragma unroll
    for (int off = 32; off > 0; off >>= 1)
        cnt += __shfl_down(cnt, off);
    if ((tid & 63) == 0) wsum[tid >> 6] = cnt;
    __syncthreads();
    if (tid == 0) {
        const int tot = wsum[0] + wsum[1] + wsum[2] + wsum[3];
        atomicAdd(out + CNT_OFF, (float)tot);
    }
}

extern "C" void kernel_launch(void* const* d_in, const int* in_sizes, int n_in,
                              void* d_out, int out_size, void* d_ws, size_t ws_size,
                              hipStream_t stream) {
    const float* vol = (const float*)d_in[0];
    float* out = (float*)d_out;

    // Zero the triangle-count slot (harness does NOT re-poison between replays).
    hipMemsetAsync((void*)(out + CNT_OFF), 0, sizeof(float), stream);

    const int blocks = (int)((NCELL + 255) / 256);
    mc_kernel<<<blocks, 256, 0, stream>>>(vol, out);
}

// Round 2
// 126.276 us; speedup vs baseline: 1.4670x; 1.4670x over previous
//
#include <hip/hip_runtime.h>

#define DIMV 128
#define CDIM 127
static constexpr long long NCELL = 127LL * 127LL * 127LL;          // 2,048,383
static constexpr long long VTX_FLOATS = NCELL * 45;                // 92,177,235
static constexpr long long CNT_OFF = NCELL * 50;                   // 102,419,150
static constexpr int FULL_BLOCKS = (int)(NCELL / 256);             // 8001

#define P1  -1
#define P4  -1,-1,-1,-1
#define P7  -1,-1,-1,-1,-1,-1,-1
#define P10 -1,-1,-1,-1,-1,-1,-1,-1,-1,-1
#define P13 -1,-1,-1,-1,-1,-1,-1,-1,-1,-1,-1,-1,-1
#define P16 -1,-1,-1,-1,-1,-1,-1,-1,-1,-1,-1,-1,-1,-1,-1,-1

__device__ __align__(16) const signed char TRI_TBL[256][16] = {
{P16},
{0,8,3,P13},
{0,1,9,P13},
{1,8,3,9,8,1,P10},
{1,2,10,P13},
{0,8,3,1,2,10,P10},
{9,2,10,0,2,9,P10},
{2,8,3,2,10,8,10,9,8,P7},
{3,11,2,P13},
{0,11,2,8,11,0,P10},
{1,9,0,2,3,11,P10},
{1,11,2,1,9,11,9,8,11,P7},
{3,10,1,11,10,3,P10},
{0,10,1,0,8,10,8,11,10,P7},
{3,9,0,3,11,9,11,10,9,P7},
{9,8,10,10,8,11,P10},
{4,7,8,P13},
{4,3,0,7,3,4,P10},
{0,1,9,8,4,7,P10},
{4,1,9,4,7,1,7,3,1,P7},
{1,2,10,8,4,7,P10},
{3,4,7,3,0,4,1,2,10,P7},
{9,2,10,9,0,2,8,4,7,P7},
{2,10,9,2,9,7,2,7,3,7,9,4,P4},
{8,4,7,3,11,2,P10},
{11,4,7,11,2,4,2,0,4,P7},
{9,0,1,8,4,7,2,3,11,P7},
{4,7,11,9,4,11,9,11,2,9,2,1,P4},
{3,10,1,3,11,10,7,8,4,P7},
{1,11,10,1,4,11,1,0,4,7,11,4,P4},
{4,7,8,9,0,11,9,11,10,11,0,3,P4},
{4,7,11,4,11,9,9,11,10,P7},
{9,5,4,P13},
{9,5,4,0,8,3,P10},
{0,5,4,1,5,0,P10},
{8,5,4,8,3,5,3,1,5,P7},
{1,2,10,9,5,4,P10},
{3,0,8,1,2,10,4,9,5,P7},
{5,2,10,5,4,2,4,0,2,P7},
{2,10,5,3,2,5,3,5,4,3,4,8,P4},
{9,5,4,2,3,11,P10},
{0,11,2,0,8,11,4,9,5,P7},
{0,5,4,0,1,5,2,3,11,P7},
{2,1,5,2,5,8,2,8,11,4,8,5,P4},
{10,3,11,10,1,3,9,5,4,P7},
{4,9,5,0,8,1,8,10,1,8,11,10,P4},
{5,4,0,5,0,11,5,11,10,11,0,3,P4},
{5,4,8,5,8,10,10,8,11,P7},
{9,7,8,5,7,9,P10},
{9,3,0,9,5,3,5,7,3,P7},
{0,7,8,0,1,7,1,5,7,P7},
{1,5,3,3,5,7,P10},
{9,7,8,9,5,7,10,1,2,P7},
{10,1,2,9,5,0,5,3,0,5,7,3,P4},
{8,0,2,8,2,5,8,5,7,10,5,2,P4},
{2,10,5,2,5,3,3,5,7,P7},
{7,9,5,7,8,9,3,11,2,P7},
{9,5,7,9,7,2,9,2,0,2,7,11,P4},
{2,3,11,0,1,8,1,7,8,1,5,7,P4},
{11,2,1,11,1,7,7,1,5,P7},
{9,5,8,8,5,7,10,1,3,10,3,11,P4},
{5,7,0,5,0,9,7,11,0,1,0,10,11,10,0,P1},
{11,10,0,11,0,3,10,5,0,8,0,7,5,7,0,P1},
{11,10,5,7,11,5,P10},
{10,6,5,P13},
{0,8,3,5,10,6,P10},
{9,0,1,5,10,6,P10},
{1,8,3,1,9,8,5,10,6,P7},
{1,6,5,2,6,1,P10},
{1,6,5,1,2,6,3,0,8,P7},
{9,6,5,9,0,6,0,2,6,P7},
{5,9,8,5,8,2,5,2,6,3,2,8,P4},
{2,3,11,10,6,5,P10},
{11,0,8,11,2,0,10,6,5,P7},
{0,1,9,2,3,11,5,10,6,P7},
{5,10,6,1,9,2,9,11,2,9,8,11,P4},
{6,3,11,6,5,3,5,1,3,P7},
{0,8,11,0,11,5,0,5,1,5,11,6,P4},
{3,11,6,0,3,6,0,6,5,0,5,9,P4},
{6,5,9,6,9,11,11,9,8,P7},
{5,10,6,4,7,8,P10},
{4,3,0,4,7,3,6,5,10,P7},
{1,9,0,5,10,6,8,4,7,P7},
{10,6,5,1,9,7,1,7,3,7,9,4,P4},
{6,1,2,6,5,1,4,7,8,P7},
{1,2,5,5,2,6,3,0,4,3,4,7,P4},
{8,4,7,9,0,5,0,6,5,0,2,6,P4},
{7,3,9,7,9,4,3,2,9,5,9,6,2,6,9,P1},
{3,11,2,7,8,4,10,6,5,P7},
{5,10,6,4,7,2,4,2,0,2,7,11,P4},
{0,1,9,4,7,8,2,3,11,5,10,6,P4},
{9,2,1,9,11,2,9,4,11,7,11,4,5,10,6,P1},
{8,4,7,3,11,5,3,5,1,5,11,6,P4},
{5,1,11,5,11,6,1,0,11,7,11,4,0,4,11,P1},
{0,5,9,0,6,5,0,3,6,11,6,3,8,4,7,P1},
{6,5,9,6,9,11,4,7,9,7,11,9,P4},
{10,4,9,6,4,10,P10},
{4,10,6,4,9,10,0,8,3,P7},
{10,0,1,10,6,0,6,4,0,P7},
{8,3,1,8,1,6,8,6,4,6,1,10,P4},
{1,4,9,1,2,4,2,6,4,P7},
{3,0,8,1,2,9,2,4,9,2,6,4,P4},
{0,2,4,4,2,6,P10},
{8,3,2,8,2,4,4,2,6,P7},
{10,4,9,10,6,4,11,2,3,P7},
{0,8,2,2,8,11,4,9,10,4,10,6,P4},
{3,11,2,0,1,6,0,6,4,6,1,10,P4},
{6,4,1,6,1,10,4,8,1,2,1,11,8,11,1,P1},
{9,6,4,9,3,6,9,1,3,11,6,3,P4},
{8,11,1,8,1,0,11,6,1,9,1,4,6,4,1,P1},
{3,11,6,3,6,0,0,6,4,P7},
{6,4,8,11,6,8,P10},
{7,10,6,7,8,10,8,9,10,P7},
{0,7,3,0,10,7,0,9,10,6,7,10,P4},
{10,6,7,1,10,7,1,7,8,1,8,0,P4},
{10,6,7,10,7,1,1,7,3,P7},
{1,2,6,1,6,8,1,8,9,8,6,7,P4},
{2,6,9,2,9,1,6,7,9,0,9,3,7,3,9,P1},
{7,8,0,7,0,6,6,0,2,P7},
{7,3,2,6,7,2,P10},
{2,3,11,10,6,8,10,8,9,8,6,7,P4},
{2,0,7,2,7,11,0,9,7,6,7,10,9,10,7,P1},
{1,8,0,1,7,8,1,10,7,6,7,10,2,3,11,P1},
{11,2,1,11,1,7,10,6,1,6,7,1,P4},
{8,9,6,8,6,7,9,1,6,11,6,3,1,3,6,P1},
{0,9,1,11,6,7,P10},
{7,8,0,7,0,6,3,11,0,11,6,0,P4},
{7,11,6,P13},
{7,6,11,P13},
{3,0,8,11,7,6,P10},
{0,1,9,11,7,6,P10},
{8,1,9,8,3,1,11,7,6,P7},
{10,1,2,6,11,7,P10},
{1,2,10,3,0,8,6,11,7,P7},
{2,9,0,2,10,9,6,11,7,P7},
{6,11,7,2,10,3,10,8,3,10,9,8,P4},
{7,2,3,6,2,7,P10},
{7,0,8,7,6,0,6,2,0,P7},
{2,7,6,2,3,7,0,1,9,P7},
{1,6,2,1,8,6,1,9,8,8,7,6,P4},
{10,7,6,10,1,7,1,3,7,P7},
{10,7,6,1,7,10,1,8,7,1,0,8,P4},
{0,3,7,0,7,10,0,10,9,6,10,7,P4},
{7,6,10,7,10,8,8,10,9,P7},
{6,8,4,11,8,6,P10},
{3,6,11,3,0,6,0,4,6,P7},
{8,6,11,8,4,6,9,0,1,P7},
{9,4,6,9,6,3,9,3,1,11,3,6,P4},
{6,8,4,6,11,8,2,10,1,P7},
{1,2,10,3,0,11,0,6,11,0,4,6,P4},
{4,11,8,4,6,11,0,2,9,2,10,9,P4},
{10,9,3,10,3,2,9,4,3,11,3,6,4,6,3,P1},
{8,2,3,8,4,2,4,6,2,P7},
{0,4,2,4,6,2,P10},
{1,9,0,2,3,4,2,4,6,4,3,8,P4},
{1,9,4,1,4,2,2,4,6,P7},
{8,1,3,8,6,1,8,4,6,6,10,1,P4},
{10,1,0,10,0,6,6,0,4,P7},
{4,6,3,4,3,8,6,10,3,0,3,9,10,9,3,P1},
{10,9,4,6,10,4,P10},
{4,9,5,7,6,11,P10},
{0,8,3,4,9,5,11,7,6,P7},
{5,0,1,5,4,0,7,6,11,P7},
{11,7,6,8,3,4,3,5,4,3,1,5,P4},
{9,5,4,10,1,2,7,6,11,P7},
{6,11,7,1,2,10,0,8,3,4,9,5,P4},
{7,6,11,5,4,10,4,2,10,4,0,2,P4},
{3,4,8,3,5,4,3,2,5,10,5,2,11,7,6,P1},
{7,2,3,7,6,2,5,4,9,P7},
{9,5,4,0,8,6,0,6,2,6,8,7,P4},
{3,6,2,3,7,6,1,5,0,5,4,0,P4},
{6,2,8,6,8,7,2,1,8,4,8,5,1,5,8,P1},
{9,5,4,10,1,6,1,7,6,1,3,7,P4},
{1,6,10,1,7,6,1,0,7,8,7,0,9,5,4,P1},
{4,0,10,4,10,5,0,3,10,6,10,7,3,7,10,P1},
{7,6,10,7,10,8,5,4,10,4,8,10,P4},
{6,9,5,6,11,9,11,8,9,P7},
{3,6,11,0,6,3,0,5,6,0,9,5,P4},
{0,11,8,0,5,11,0,1,5,5,6,11,P4},
{6,11,3,6,3,5,5,3,1,P7},
{1,2,10,9,5,11,9,11,8,11,5,6,P4},
{0,11,3,0,6,11,0,9,6,5,6,9,1,2,10,P1},
{11,8,5,11,5,6,8,0,5,10,5,2,0,2,5,P1},
{6,11,3,6,3,5,2,10,3,10,5,3,P4},
{5,8,9,5,2,8,5,6,2,3,8,2,P4},
{9,5,6,9,6,0,0,6,2,P7},
{1,5,8,1,8,0,5,6,8,3,8,2,6,2,8,P1},
{1,5,6,2,1,6,P10},
{1,3,6,1,6,10,3,8,6,5,6,9,8,9,6,P1},
{10,1,0,10,0,6,9,5,0,5,6,0,P4},
{0,3,8,5,6,10,P10},
{10,5,6,P13},
{11,5,10,7,5,11,P10},
{11,5,10,11,7,5,8,3,0,P7},
{5,11,7,5,10,11,1,9,0,P7},
{10,7,5,10,11,7,9,8,1,8,3,1,P4},
{11,1,2,11,7,1,7,5,1,P7},
{0,8,3,1,2,7,1,7,5,7,2,11,P4},
{9,7,5,9,2,7,9,0,2,2,11,7,P4},
{7,5,2,7,2,11,5,9,2,3,2,8,9,8,2,P1},
{2,5,10,2,3,5,3,7,5,P7},
{8,2,0,8,5,2,8,7,5,10,2,5,P4},
{9,0,1,5,10,3,5,3,7,3,10,2,P4},
{9,8,2,9,2,1,8,7,2,10,2,5,7,5,2,P1},
{1,3,5,3,7,5,P10},
{0,8,7,0,7,1,1,7,5,P7},
{9,0,3,9,3,5,5,3,7,P7},
{9,8,7,5,9,7,P10},
{5,8,4,5,10,8,10,11,8,P7},
{5,0,4,5,11,0,5,10,11,11,3,0,P4},
{0,1,9,8,4,10,8,10,11,10,4,5,P4},
{10,11,4,10,4,5,11,3,4,9,4,1,3,1,4,P1},
{2,5,1,2,8,5,2,11,8,4,5,8,P4},
{0,4,11,0,11,3,4,5,11,2,11,1,5,1,11,P1},
{0,2,5,0,5,9,2,11,5,4,5,8,11,8,5,P1},
{9,4,5,2,11,3,P10},
{2,5,10,3,5,2,3,4,5,3,8,4,P4},
{5,10,2,5,2,4,4,2,0,P7},
{3,10,2,3,5,10,3,8,5,4,5,8,0,1,9,P1},
{5,10,2,5,2,4,1,9,2,9,4,2,P4},
{8,4,5,8,5,3,3,5,1,P7},
{0,4,5,1,0,5,P10},
{8,4,5,8,5,3,9,0,5,0,3,5,P4},
{9,4,5,P13},
{4,11,7,4,9,11,9,10,11,P7},
{0,8,3,4,9,7,9,11,7,9,10,11,P4},
{1,10,11,1,11,4,1,4,0,7,4,11,P4},
{3,1,4,3,4,8,1,10,4,7,4,11,10,11,4,P1},
{4,11,7,9,11,4,9,2,11,9,1,2,P4},
{9,7,4,9,11,7,9,1,11,2,11,1,0,8,3,P1},
{11,7,4,11,4,2,2,4,0,P7},
{11,7,4,11,4,2,8,3,4,3,2,4,P4},
{2,9,10,2,7,9,2,3,7,7,4,9,P4},
{9,10,7,9,7,4,10,2,7,8,7,0,2,0,7,P1},
{3,7,10,3,10,2,7,4,10,1,10,0,4,0,10,P1},
{1,10,2,8,7,4,P10},
{4,9,1,4,1,7,7,1,3,P7},
{4,9,1,4,1,7,0,8,1,8,7,1,P4},
{4,0,3,7,4,3,P10},
{4,8,7,P13},
{9,10,8,10,11,8,P10},
{3,0,9,3,9,11,11,9,10,P7},
{0,1,10,0,10,8,8,10,11,P7},
{3,1,10,11,3,10,P10},
{1,2,11,1,11,9,9,11,8,P7},
{3,0,9,3,9,11,1,2,9,2,11,9,P4},
{0,2,11,8,0,11,P10},
{3,2,11,P13},
{2,3,8,2,8,10,10,8,9,P7},
{9,10,2,0,9,2,P10},
{2,3,8,2,8,10,0,1,8,1,10,8,P4},
{1,10,2,P13},
{1,3,8,9,1,8,P10},
{0,9,1,P13},
{0,3,8,P13},
{P16}
};

__global__ __launch_bounds__(256) void mc_kernel(const float* __restrict__ vol,
                                                 float* __restrict__ out) {
    // ev_s[cell][37]: pad 37 -> phase-1 write bank (5*tid+r)%32 conflict-free,
    // phase-2 gather spreads cells across banks.
    __shared__ float ev_s[256 * 37];          // 37888 B
    __shared__ signed char rows_b[256 * 16];  // 4096 B
    __shared__ int wsum[4];

    const int tid = threadIdx.x;
    const long long cell = (long long)blockIdx.x * 256 + tid;
    const bool active = cell < NCELL;
    int cnt = 0;
    int4 row = make_int4(-1, -1, -1, -1);

    if (active) {
        const int x = (int)(cell % CDIM);
        const int r = (int)(cell / CDIM);
        const int y = r % CDIM;
        const int z = r / CDIM;

        const float* p = vol + ((size_t)z * DIMV + y) * DIMV + x;
        float cv[8];
        cv[0] = p[0];
        cv[1] = p[1];
        cv[3] = p[DIMV];
        cv[2] = p[DIMV + 1];
        cv[4] = p[DIMV * DIMV];
        cv[5] = p[DIMV * DIMV + 1];
        cv[7] = p[DIMV * DIMV + DIMV];
        cv[6] = p[DIMV * DIMV + DIMV + 1];

        int cidx = 0;
#pragma unroll
        for (int k = 0; k < 8; ++k)
            cidx |= (cv[k] < 0.5f) ? (1 << k) : 0;

        row = ((const int4*)TRI_TBL)[cidx];

        const int   EA[12] = {0,1,2,3,4,5,6,7,0,1,2,3};
        const int   EB[12] = {1,2,3,0,5,6,7,4,4,5,6,7};
        const float OX[8]  = {0,1,1,0,0,1,1,0};
        const float OY[8]  = {0,0,1,1,0,0,1,1};
        const float OZ[8]  = {0,0,0,0,1,1,1,1};

        const float xf = (float)x, yf = (float)y, zf = (float)z;
        float* evp = &ev_s[tid * 37];
#pragma unroll
        for (int e = 0; e < 12; ++e) {
            const float v1 = cv[EA[e]];
            const float v2 = cv[EB[e]];
            const float d  = v2 - v1;
            const float t  = (fabsf(d) > 1e-9f) ? ((0.5f - v1) / d) : 0.5f;
            evp[3*e + 0] = xf + OX[EA[e]] + t * (OX[EB[e]] - OX[EA[e]]);
            evp[3*e + 1] = yf + OY[EA[e]] + t * (OY[EB[e]] - OY[EA[e]]);
            evp[3*e + 2] = zf + OZ[EA[e]] + t * (OZ[EB[e]] - OZ[EA[e]]);
        }

        // triangle count: table bytes 0,3,6,9,12
        cnt += ((signed char)( row.x        & 0xFF) >= 0) ? 1 : 0;
        cnt += ((signed char)((row.x >> 24) & 0xFF) >= 0) ? 1 : 0;
        cnt += ((signed char)((row.y >> 16) & 0xFF) >= 0) ? 1 : 0;
        cnt += ((signed char)((row.z >>  8) & 0xFF) >= 0) ? 1 : 0;
        cnt += ((signed char)( row.w        & 0xFF) >= 0) ? 1 : 0;
    }
    ((int4*)rows_b)[tid] = row;
    __syncthreads();

    if (blockIdx.x < FULL_BLOCKS) {
        // ---- Phase 2 fast path: fully coalesced float4 vertex writes ----
        float4* vout = (float4*)(out + (size_t)blockIdx.x * (256 * 45));
#pragma unroll
        for (int k = 0; k < 12; ++k) {
            const int i4 = tid + k * 256;
            if (k == 11 && i4 >= 2880) break;   // 2880 = 256*45/4
            const int q0 = 4 * i4;
            uint c  = (uint)q0 / 45u;
            uint cm = (uint)q0 - c * 45u;
            float vv[4];
#pragma unroll
            for (int j = 0; j < 4; ++j) {
                const uint b    = cm / 3u;
                const uint axis = cm - b * 3u;
                const int  eb   = (int)rows_b[c * 16 + b];
                const uint idx  = (eb >= 0) ? (3u * (uint)eb + axis) : 0u;
                const float val = ev_s[c * 37 + idx];
                vv[j] = (eb >= 0) ? val : 0.0f;
                ++cm;
                if (cm == 45u) { cm = 0u; ++c; }
            }
            vout[i4] = make_float4(vv[0], vv[1], vv[2], vv[3]);
        }

        // ---- tri_valid: coalesced scalar dwords (region only 4B-aligned) ----
        float* tvout = out + VTX_FLOATS + (size_t)blockIdx.x * (256 * 5);
#pragma unroll
        for (int k = 0; k < 5; ++k) {
            const int i = tid + k * 256;
            const uint c  = (uint)i / 5u;
            const uint t5 = (uint)i - c * 5u;
            tvout[i] = ((int)rows_b[c * 16 + 3 * t5] >= 0) ? 1.0f : 0.0f;
        }
    } else if (active) {
        // ---- Partial last block (127 cells): scalar fallback ----
        const float* evp = &ev_s[tid * 37];
        const size_t vb  = (size_t)cell * 45;
        const size_t tvb = (size_t)VTX_FLOATS + (size_t)cell * 5;
        const signed char* rb = &rows_b[tid * 16];
#pragma unroll
        for (int t5 = 0; t5 < 5; ++t5) {
            float* o = out + vb + 9 * t5;
#pragma unroll
            for (int v3 = 0; v3 < 3; ++v3) {
                const int eb = (int)rb[3 * t5 + v3];
                const int j  = (eb >= 0) ? eb : 0;
                const float mm = (eb >= 0) ? 1.0f : 0.0f;
                o[3*v3 + 0] = evp[3*j + 0] * mm;
                o[3*v3 + 1] = evp[3*j + 1] * mm;
                o[3*v3 + 2] = evp[3*j + 2] * mm;
            }
            out[tvb + t5] = ((int)rb[3 * t5] >= 0) ? 1.0f : 0.0f;
        }
    }

    // Block-level count reduction -> one float atomic per block.
#pragma unroll
    for (int off = 32; off > 0; off >>= 1)
        cnt += __shfl_down(cnt, off);
    if ((tid & 63) == 0) wsum[tid >> 6] = cnt;
    __syncthreads();
    if (tid == 0) {
        const int tot = wsum[0] + wsum[1] + wsum[2] + wsum[3];
        atomicAdd(out + CNT_OFF, (float)tot);
    }
}

extern "C" void kernel_launch(void* const* d_in, const int* in_sizes, int n_in,
                              void* d_out, int out_size, void* d_ws, size_t ws_size,
                              hipStream_t stream) {
    const float* vol = (const float*)d_in[0];
    float* out = (float*)d_out;

    // Zero the triangle-count slot (harness does NOT re-poison between replays).
    hipMemsetAsync((void*)(out + CNT_OFF), 0, sizeof(float), stream);

    const int blocks = (int)((NCELL + 255) / 256);
    mc_kernel<<<blocks, 256, 0, stream>>>(vol, out);
}

// Round 4
// 119.883 us; speedup vs baseline: 1.5453x; 1.0533x over previous
//
#include <hip/hip_runtime.h>

#define DIMV 128
#define CDIM 127
static constexpr long long NCELL = 127LL * 127LL * 127LL;          // 2,048,383
static constexpr long long VTX_FLOATS = NCELL * 45;                // 92,177,235
static constexpr long long CNT_OFF = NCELL * 50;                   // 102,419,150
static constexpr int FULL_BLOCKS = (int)(NCELL / 256);             // 8001

#define P1  -1
#define P4  -1,-1,-1,-1
#define P7  -1,-1,-1,-1,-1,-1,-1
#define P10 -1,-1,-1,-1,-1,-1,-1,-1,-1,-1
#define P13 -1,-1,-1,-1,-1,-1,-1,-1,-1,-1,-1,-1,-1
#define P16 -1,-1,-1,-1,-1,-1,-1,-1,-1,-1,-1,-1,-1,-1,-1,-1

__device__ __align__(16) const signed char TRI_TBL[256][16] = {
{P16},
{0,8,3,P13},
{0,1,9,P13},
{1,8,3,9,8,1,P10},
{1,2,10,P13},
{0,8,3,1,2,10,P10},
{9,2,10,0,2,9,P10},
{2,8,3,2,10,8,10,9,8,P7},
{3,11,2,P13},
{0,11,2,8,11,0,P10},
{1,9,0,2,3,11,P10},
{1,11,2,1,9,11,9,8,11,P7},
{3,10,1,11,10,3,P10},
{0,10,1,0,8,10,8,11,10,P7},
{3,9,0,3,11,9,11,10,9,P7},
{9,8,10,10,8,11,P10},
{4,7,8,P13},
{4,3,0,7,3,4,P10},
{0,1,9,8,4,7,P10},
{4,1,9,4,7,1,7,3,1,P7},
{1,2,10,8,4,7,P10},
{3,4,7,3,0,4,1,2,10,P7},
{9,2,10,9,0,2,8,4,7,P7},
{2,10,9,2,9,7,2,7,3,7,9,4,P4},
{8,4,7,3,11,2,P10},
{11,4,7,11,2,4,2,0,4,P7},
{9,0,1,8,4,7,2,3,11,P7},
{4,7,11,9,4,11,9,11,2,9,2,1,P4},
{3,10,1,3,11,10,7,8,4,P7},
{1,11,10,1,4,11,1,0,4,7,11,4,P4},
{4,7,8,9,0,11,9,11,10,11,0,3,P4},
{4,7,11,4,11,9,9,11,10,P7},
{9,5,4,P13},
{9,5,4,0,8,3,P10},
{0,5,4,1,5,0,P10},
{8,5,4,8,3,5,3,1,5,P7},
{1,2,10,9,5,4,P10},
{3,0,8,1,2,10,4,9,5,P7},
{5,2,10,5,4,2,4,0,2,P7},
{2,10,5,3,2,5,3,5,4,3,4,8,P4},
{9,5,4,2,3,11,P10},
{0,11,2,0,8,11,4,9,5,P7},
{0,5,4,0,1,5,2,3,11,P7},
{2,1,5,2,5,8,2,8,11,4,8,5,P4},
{10,3,11,10,1,3,9,5,4,P7},
{4,9,5,0,8,1,8,10,1,8,11,10,P4},
{5,4,0,5,0,11,5,11,10,11,0,3,P4},
{5,4,8,5,8,10,10,8,11,P7},
{9,7,8,5,7,9,P10},
{9,3,0,9,5,3,5,7,3,P7},
{0,7,8,0,1,7,1,5,7,P7},
{1,5,3,3,5,7,P10},
{9,7,8,9,5,7,10,1,2,P7},
{10,1,2,9,5,0,5,3,0,5,7,3,P4},
{8,0,2,8,2,5,8,5,7,10,5,2,P4},
{2,10,5,2,5,3,3,5,7,P7},
{7,9,5,7,8,9,3,11,2,P7},
{9,5,7,9,7,2,9,2,0,2,7,11,P4},
{2,3,11,0,1,8,1,7,8,1,5,7,P4},
{11,2,1,11,1,7,7,1,5,P7},
{9,5,8,8,5,7,10,1,3,10,3,11,P4},
{5,7,0,5,0,9,7,11,0,1,0,10,11,10,0,P1},
{11,10,0,11,0,3,10,5,0,8,0,7,5,7,0,P1},
{11,10,5,7,11,5,P10},
{10,6,5,P13},
{0,8,3,5,10,6,P10},
{9,0,1,5,10,6,P10},
{1,8,3,1,9,8,5,10,6,P7},
{1,6,5,2,6,1,P10},
{1,6,5,1,2,6,3,0,8,P7},
{9,6,5,9,0,6,0,2,6,P7},
{5,9,8,5,8,2,5,2,6,3,2,8,P4},
{2,3,11,10,6,5,P10},
{11,0,8,11,2,0,10,6,5,P7},
{0,1,9,2,3,11,5,10,6,P7},
{5,10,6,1,9,2,9,11,2,9,8,11,P4},
{6,3,11,6,5,3,5,1,3,P7},
{0,8,11,0,11,5,0,5,1,5,11,6,P4},
{3,11,6,0,3,6,0,6,5,0,5,9,P4},
{6,5,9,6,9,11,11,9,8,P7},
{5,10,6,4,7,8,P10},
{4,3,0,4,7,3,6,5,10,P7},
{1,9,0,5,10,6,8,4,7,P7},
{10,6,5,1,9,7,1,7,3,7,9,4,P4},
{6,1,2,6,5,1,4,7,8,P7},
{1,2,5,5,2,6,3,0,4,3,4,7,P4},
{8,4,7,9,0,5,0,6,5,0,2,6,P4},
{7,3,9,7,9,4,3,2,9,5,9,6,2,6,9,P1},
{3,11,2,7,8,4,10,6,5,P7},
{5,10,6,4,7,2,4,2,0,2,7,11,P4},
{0,1,9,4,7,8,2,3,11,5,10,6,P4},
{9,2,1,9,11,2,9,4,11,7,11,4,5,10,6,P1},
{8,4,7,3,11,5,3,5,1,5,11,6,P4},
{5,1,11,5,11,6,1,0,11,7,11,4,0,4,11,P1},
{0,5,9,0,6,5,0,3,6,11,6,3,8,4,7,P1},
{6,5,9,6,9,11,4,7,9,7,11,9,P4},
{10,4,9,6,4,10,P10},
{4,10,6,4,9,10,0,8,3,P7},
{10,0,1,10,6,0,6,4,0,P7},
{8,3,1,8,1,6,8,6,4,6,1,10,P4},
{1,4,9,1,2,4,2,6,4,P7},
{3,0,8,1,2,9,2,4,9,2,6,4,P4},
{0,2,4,4,2,6,P10},
{8,3,2,8,2,4,4,2,6,P7},
{10,4,9,10,6,4,11,2,3,P7},
{0,8,2,2,8,11,4,9,10,4,10,6,P4},
{3,11,2,0,1,6,0,6,4,6,1,10,P4},
{6,4,1,6,1,10,4,8,1,2,1,11,8,11,1,P1},
{9,6,4,9,3,6,9,1,3,11,6,3,P4},
{8,11,1,8,1,0,11,6,1,9,1,4,6,4,1,P1},
{3,11,6,3,6,0,0,6,4,P7},
{6,4,8,11,6,8,P10},
{7,10,6,7,8,10,8,9,10,P7},
{0,7,3,0,10,7,0,9,10,6,7,10,P4},
{10,6,7,1,10,7,1,7,8,1,8,0,P4},
{10,6,7,10,7,1,1,7,3,P7},
{1,2,6,1,6,8,1,8,9,8,6,7,P4},
{2,6,9,2,9,1,6,7,9,0,9,3,7,3,9,P1},
{7,8,0,7,0,6,6,0,2,P7},
{7,3,2,6,7,2,P10},
{2,3,11,10,6,8,10,8,9,8,6,7,P4},
{2,0,7,2,7,11,0,9,7,6,7,10,9,10,7,P1},
{1,8,0,1,7,8,1,10,7,6,7,10,2,3,11,P1},
{11,2,1,11,1,7,10,6,1,6,7,1,P4},
{8,9,6,8,6,7,9,1,6,11,6,3,1,3,6,P1},
{0,9,1,11,6,7,P10},
{7,8,0,7,0,6,3,11,0,11,6,0,P4},
{7,11,6,P13},
{7,6,11,P13},
{3,0,8,11,7,6,P10},
{0,1,9,11,7,6,P10},
{8,1,9,8,3,1,11,7,6,P7},
{10,1,2,6,11,7,P10},
{1,2,10,3,0,8,6,11,7,P7},
{2,9,0,2,10,9,6,11,7,P7},
{6,11,7,2,10,3,10,8,3,10,9,8,P4},
{7,2,3,6,2,7,P10},
{7,0,8,7,6,0,6,2,0,P7},
{2,7,6,2,3,7,0,1,9,P7},
{1,6,2,1,8,6,1,9,8,8,7,6,P4},
{10,7,6,10,1,7,1,3,7,P7},
{10,7,6,1,7,10,1,8,7,1,0,8,P4},
{0,3,7,0,7,10,0,10,9,6,10,7,P4},
{7,6,10,7,10,8,8,10,9,P7},
{6,8,4,11,8,6,P10},
{3,6,11,3,0,6,0,4,6,P7},
{8,6,11,8,4,6,9,0,1,P7},
{9,4,6,9,6,3,9,3,1,11,3,6,P4},
{6,8,4,6,11,8,2,10,1,P7},
{1,2,10,3,0,11,0,6,11,0,4,6,P4},
{4,11,8,4,6,11,0,2,9,2,10,9,P4},
{10,9,3,10,3,2,9,4,3,11,3,6,4,6,3,P1},
{8,2,3,8,4,2,4,6,2,P7},
{0,4,2,4,6,2,P10},
{1,9,0,2,3,4,2,4,6,4,3,8,P4},
{1,9,4,1,4,2,2,4,6,P7},
{8,1,3,8,6,1,8,4,6,6,10,1,P4},
{10,1,0,10,0,6,6,0,4,P7},
{4,6,3,4,3,8,6,10,3,0,3,9,10,9,3,P1},
{10,9,4,6,10,4,P10},
{4,9,5,7,6,11,P10},
{0,8,3,4,9,5,11,7,6,P7},
{5,0,1,5,4,0,7,6,11,P7},
{11,7,6,8,3,4,3,5,4,3,1,5,P4},
{9,5,4,10,1,2,7,6,11,P7},
{6,11,7,1,2,10,0,8,3,4,9,5,P4},
{7,6,11,5,4,10,4,2,10,4,0,2,P4},
{3,4,8,3,5,4,3,2,5,10,5,2,11,7,6,P1},
{7,2,3,7,6,2,5,4,9,P7},
{9,5,4,0,8,6,0,6,2,6,8,7,P4},
{3,6,2,3,7,6,1,5,0,5,4,0,P4},
{6,2,8,6,8,7,2,1,8,4,8,5,1,5,8,P1},
{9,5,4,10,1,6,1,7,6,1,3,7,P4},
{1,6,10,1,7,6,1,0,7,8,7,0,9,5,4,P1},
{4,0,10,4,10,5,0,3,10,6,10,7,3,7,10,P1},
{7,6,10,7,10,8,5,4,10,4,8,10,P4},
{6,9,5,6,11,9,11,8,9,P7},
{3,6,11,0,6,3,0,5,6,0,9,5,P4},
{0,11,8,0,5,11,0,1,5,5,6,11,P4},
{6,11,3,6,3,5,5,3,1,P7},
{1,2,10,9,5,11,9,11,8,11,5,6,P4},
{0,11,3,0,6,11,0,9,6,5,6,9,1,2,10,P1},
{11,8,5,11,5,6,8,0,5,10,5,2,0,2,5,P1},
{6,11,3,6,3,5,2,10,3,10,5,3,P4},
{5,8,9,5,2,8,5,6,2,3,8,2,P4},
{9,5,6,9,6,0,0,6,2,P7},
{1,5,8,1,8,0,5,6,8,3,8,2,6,2,8,P1},
{1,5,6,2,1,6,P10},
{1,3,6,1,6,10,3,8,6,5,6,9,8,9,6,P1},
{10,1,0,10,0,6,9,5,0,5,6,0,P4},
{0,3,8,5,6,10,P10},
{10,5,6,P13},
{11,5,10,7,5,11,P10},
{11,5,10,11,7,5,8,3,0,P7},
{5,11,7,5,10,11,1,9,0,P7},
{10,7,5,10,11,7,9,8,1,8,3,1,P4},
{11,1,2,11,7,1,7,5,1,P7},
{0,8,3,1,2,7,1,7,5,7,2,11,P4},
{9,7,5,9,2,7,9,0,2,2,11,7,P4},
{7,5,2,7,2,11,5,9,2,3,2,8,9,8,2,P1},
{2,5,10,2,3,5,3,7,5,P7},
{8,2,0,8,5,2,8,7,5,10,2,5,P4},
{9,0,1,5,10,3,5,3,7,3,10,2,P4},
{9,8,2,9,2,1,8,7,2,10,2,5,7,5,2,P1},
{1,3,5,3,7,5,P10},
{0,8,7,0,7,1,1,7,5,P7},
{9,0,3,9,3,5,5,3,7,P7},
{9,8,7,5,9,7,P10},
{5,8,4,5,10,8,10,11,8,P7},
{5,0,4,5,11,0,5,10,11,11,3,0,P4},
{0,1,9,8,4,10,8,10,11,10,4,5,P4},
{10,11,4,10,4,5,11,3,4,9,4,1,3,1,4,P1},
{2,5,1,2,8,5,2,11,8,4,5,8,P4},
{0,4,11,0,11,3,4,5,11,2,11,1,5,1,11,P1},
{0,2,5,0,5,9,2,11,5,4,5,8,11,8,5,P1},
{9,4,5,2,11,3,P10},
{2,5,10,3,5,2,3,4,5,3,8,4,P4},
{5,10,2,5,2,4,4,2,0,P7},
{3,10,2,3,5,10,3,8,5,4,5,8,0,1,9,P1},
{5,10,2,5,2,4,1,9,2,9,4,2,P4},
{8,4,5,8,5,3,3,5,1,P7},
{0,4,5,1,0,5,P10},
{8,4,5,8,5,3,9,0,5,0,3,5,P4},
{9,4,5,P13},
{4,11,7,4,9,11,9,10,11,P7},
{0,8,3,4,9,7,9,11,7,9,10,11,P4},
{1,10,11,1,11,4,1,4,0,7,4,11,P4},
{3,1,4,3,4,8,1,10,4,7,4,11,10,11,4,P1},
{4,11,7,9,11,4,9,2,11,9,1,2,P4},
{9,7,4,9,11,7,9,1,11,2,11,1,0,8,3,P1},
{11,7,4,11,4,2,2,4,0,P7},
{11,7,4,11,4,2,8,3,4,3,2,4,P4},
{2,9,10,2,7,9,2,3,7,7,4,9,P4},
{9,10,7,9,7,4,10,2,7,8,7,0,2,0,7,P1},
{3,7,10,3,10,2,7,4,10,1,10,0,4,0,10,P1},
{1,10,2,8,7,4,P10},
{4,9,1,4,1,7,7,1,3,P7},
{4,9,1,4,1,7,0,8,1,8,7,1,P4},
{4,0,3,7,4,3,P10},
{4,8,7,P13},
{9,10,8,10,11,8,P10},
{3,0,9,3,9,11,11,9,10,P7},
{0,1,10,0,10,8,8,10,11,P7},
{3,1,10,11,3,10,P10},
{1,2,11,1,11,9,9,11,8,P7},
{3,0,9,3,9,11,1,2,9,2,11,9,P4},
{0,2,11,8,0,11,P10},
{3,2,11,P13},
{2,3,8,2,8,10,10,8,9,P7},
{9,10,2,0,9,2,P10},
{2,3,8,2,8,10,0,1,8,1,10,8,P4},
{1,10,2,P13},
{1,3,8,9,1,8,P10},
{0,9,1,P13},
{0,3,8,P13},
{P16}
};

// Packed per-edge corner-offset bits, indexed by edge e in [0,12):
// AX[e]=OX[EA[e]], BX[e]=OX[EB[e]], etc.  (bit 12 = 0, used for invalid slots)
#define MAX_ 0x666
#define MBX_ 0x633
#define MAY_ 0xCCC
#define MBY_ 0xC66
#define MAZ_ 0x0F0
#define MBZ_ 0xFF0

__global__ __launch_bounds__(256) void mc_kernel(const float* __restrict__ vol,
                                                 float* __restrict__ out) {
    __shared__ float t_s[256 * 13];                    // 13312 B (slot 12 = 0)
    __shared__ __align__(16) float exp_s[256 * 45];    // 46080 B: final layout
    __shared__ unsigned char tvm_s[256];
    __shared__ int wsum[4];

    const int tid = threadIdx.x;
    const long long cell = (long long)blockIdx.x * 256 + tid;
    const bool active = cell < NCELL;

    const int x = (int)(cell % CDIM);
    const int r = (int)(cell / CDIM);
    const int y = r % CDIM;
    const int z = r / CDIM;
    const float xf = (float)x, yf = (float)y, zf = (float)z;

    int4 row = make_int4(-1, -1, -1, -1);
    float tv[12];
#pragma unroll
    for (int e = 0; e < 12; ++e) tv[e] = 0.0f;

    if (active) {
        const float* p = vol + ((size_t)z * DIMV + y) * DIMV + x;
        float cv[8];
        cv[0] = p[0];
        cv[1] = p[1];
        cv[3] = p[DIMV];
        cv[2] = p[DIMV + 1];
        cv[4] = p[DIMV * DIMV];
        cv[5] = p[DIMV * DIMV + 1];
        cv[7] = p[DIMV * DIMV + DIMV];
        cv[6] = p[DIMV * DIMV + DIMV + 1];

        int cidx = 0;
#pragma unroll
        for (int k = 0; k < 8; ++k)
            cidx |= (cv[k] < 0.5f) ? (1 << k) : 0;

        row = ((const int4*)TRI_TBL)[cidx];

        const int EA[12] = {0,1,2,3,4,5,6,7,0,1,2,3};
        const int EB[12] = {1,2,3,0,5,6,7,4,4,5,6,7};
#pragma unroll
        for (int e = 0; e < 12; ++e) {
            const float v1 = cv[EA[e]];
            const float v2 = cv[EB[e]];
            const float d  = v2 - v1;
            tv[e] = (fabsf(d) > 1e-9f) ? ((0.5f - v1) / d) : 0.5f;
        }
    }

    // Own-column LDS "spill" for runtime edge indexing (no barrier needed:
    // only this thread reads its column).
    float* tp = &t_s[tid * 13];
#pragma unroll
    for (int e = 0; e < 12; ++e) tp[e] = tv[e];
    tp[12] = 0.0f;

    const int rw[4] = {row.x, row.y, row.z, row.w};

    // tri_valid bitmask (bytes 0,3,6,9,12 of the row)
    int m = 0;
#pragma unroll
    for (int t5 = 0; t5 < 5; ++t5) {
        const int b = 3 * t5;
        const int eb = (int)(signed char)((rw[b >> 2] >> ((b & 3) * 8)) & 0xFF);
        m |= (eb >= 0) ? (1 << t5) : 0;
    }
    tvm_s[tid] = (unsigned char)m;
    int cnt = __popc(m);

    // ---- Expansion: own cell's 45 output floats -> exp_s (final layout) ----
    float* ep = &exp_s[tid * 45];
#pragma unroll
    for (int b = 0; b < 15; ++b) {
        const int eb = (int)(signed char)((rw[b >> 2] >> ((b & 3) * 8)) & 0xFF);
        const bool ok = (eb >= 0);
        const int ec = ok ? eb : 12;
        const float t = tp[ec];
        const int ax = (MAX_ >> ec) & 1, bx = (MBX_ >> ec) & 1;
        const int ay = (MAY_ >> ec) & 1, by = (MBY_ >> ec) & 1;
        const int az = (MAZ_ >> ec) & 1, bz = (MBZ_ >> ec) & 1;
        float vx = (xf + (float)ax) + t * (float)(bx - ax);
        float vy = (yf + (float)ay) + t * (float)(by - ay);
        float vz = (zf + (float)az) + t * (float)(bz - az);
        ep[3*b + 0] = ok ? vx : 0.0f;
        ep[3*b + 1] = ok ? vy : 0.0f;
        ep[3*b + 2] = ok ? vz : 0.0f;
    }
    __syncthreads();

    // ---- Stream LDS -> global ----
    const size_t base45 = (size_t)blockIdx.x * (256 * 45);
    float4* vout = (float4*)(out + base45);
    const float4* vin = (const float4*)exp_s;

    if (blockIdx.x < FULL_BLOCKS) {
        // 2880 float4s: 11 full rounds + 64-lane tail. Independent copies.
#pragma unroll
        for (int k = 0; k < 11; ++k)
            vout[tid + k * 256] = vin[tid + k * 256];
        if (tid < 64)
            vout[tid + 2816] = vin[tid + 2816];

        float* tvout = out + VTX_FLOATS + (size_t)blockIdx.x * (256 * 5);
#pragma unroll
        for (int k = 0; k < 5; ++k) {
            const int i = tid + k * 256;
            const uint c  = (uint)i / 5u;
            const uint t5 = (uint)i - c * 5u;
            tvout[i] = ((tvm_s[c] >> t5) & 1) ? 1.0f : 0.0f;
        }
    } else {
        // Last block: 127 cells -> 5715 floats = 1428 float4 + 3 tail floats.
        const int nfull4 = 1428;
        for (int i4 = tid; i4 < nfull4; i4 += 256)
            vout[i4] = vin[i4];
        if (tid < 3)
            out[base45 + 5712 + tid] = exp_s[5712 + tid];

        float* tvout = out + VTX_FLOATS + (size_t)blockIdx.x * (256 * 5);
        const int ntv = 127 * 5;
#pragma unroll
        for (int k = 0; k < 3; ++k) {
            const int i = tid + k * 256;
            if (i < ntv) {
                const uint c  = (uint)i / 5u;
                const uint t5 = (uint)i - c * 5u;
                tvout[i] = ((tvm_s[c] >> t5) & 1) ? 1.0f : 0.0f;
            }
        }
    }

    // Block-level count reduction -> one float atomic per block.
#pragma unroll
    for (int off = 32; off > 0; off >>= 1)
        cnt += __shfl_down(cnt, off);
    if ((tid & 63) == 0) wsum[tid >> 6] = cnt;
    __syncthreads();
    if (tid == 0) {
        const int tot = wsum[0] + wsum[1] + wsum[2] + wsum[3];
        atomicAdd(out + CNT_OFF, (float)tot);
    }
}

extern "C" void kernel_launch(void* const* d_in, const int* in_sizes, int n_in,
                              void* d_out, int out_size, void* d_ws, size_t ws_size,
                              hipStream_t stream) {
    const float* vol = (const float*)d_in[0];
    float* out = (float*)d_out;

    // Zero the triangle-count slot (harness does NOT re-poison between replays).
    hipMemsetAsync((void*)(out + CNT_OFF), 0, sizeof(float), stream);

    const int blocks = (int)((NCELL + 255) / 256);
    mc_kernel<<<blocks, 256, 0, stream>>>(vol, out);
}

// Round 5
// 85.770 us; speedup vs baseline: 2.1598x; 1.3977x over previous
//
#include <hip/hip_runtime.h>

#define DIMV 128
#define CDIM 127
static constexpr long long NCELL = 127LL * 127LL * 127LL;          // 2,048,383
static constexpr long long VTX_FLOATS = NCELL * 45;                // 92,177,235
static constexpr long long CNT_OFF = NCELL * 50;                   // 102,419,150
static constexpr int NBLK = (int)((NCELL + 255) / 256);            // 8002
static constexpr int FULL_BLOCKS = (int)(NCELL / 256);             // 8001

#define P1  -1
#define P4  -1,-1,-1,-1
#define P7  -1,-1,-1,-1,-1,-1,-1
#define P10 -1,-1,-1,-1,-1,-1,-1,-1,-1,-1
#define P13 -1,-1,-1,-1,-1,-1,-1,-1,-1,-1,-1,-1,-1
#define P16 -1,-1,-1,-1,-1,-1,-1,-1,-1,-1,-1,-1,-1,-1,-1,-1

__device__ __align__(16) const signed char TRI_TBL[256][16] = {
{P16},
{0,8,3,P13},
{0,1,9,P13},
{1,8,3,9,8,1,P10},
{1,2,10,P13},
{0,8,3,1,2,10,P10},
{9,2,10,0,2,9,P10},
{2,8,3,2,10,8,10,9,8,P7},
{3,11,2,P13},
{0,11,2,8,11,0,P10},
{1,9,0,2,3,11,P10},
{1,11,2,1,9,11,9,8,11,P7},
{3,10,1,11,10,3,P10},
{0,10,1,0,8,10,8,11,10,P7},
{3,9,0,3,11,9,11,10,9,P7},
{9,8,10,10,8,11,P10},
{4,7,8,P13},
{4,3,0,7,3,4,P10},
{0,1,9,8,4,7,P10},
{4,1,9,4,7,1,7,3,1,P7},
{1,2,10,8,4,7,P10},
{3,4,7,3,0,4,1,2,10,P7},
{9,2,10,9,0,2,8,4,7,P7},
{2,10,9,2,9,7,2,7,3,7,9,4,P4},
{8,4,7,3,11,2,P10},
{11,4,7,11,2,4,2,0,4,P7},
{9,0,1,8,4,7,2,3,11,P7},
{4,7,11,9,4,11,9,11,2,9,2,1,P4},
{3,10,1,3,11,10,7,8,4,P7},
{1,11,10,1,4,11,1,0,4,7,11,4,P4},
{4,7,8,9,0,11,9,11,10,11,0,3,P4},
{4,7,11,4,11,9,9,11,10,P7},
{9,5,4,P13},
{9,5,4,0,8,3,P10},
{0,5,4,1,5,0,P10},
{8,5,4,8,3,5,3,1,5,P7},
{1,2,10,9,5,4,P10},
{3,0,8,1,2,10,4,9,5,P7},
{5,2,10,5,4,2,4,0,2,P7},
{2,10,5,3,2,5,3,5,4,3,4,8,P4},
{9,5,4,2,3,11,P10},
{0,11,2,0,8,11,4,9,5,P7},
{0,5,4,0,1,5,2,3,11,P7},
{2,1,5,2,5,8,2,8,11,4,8,5,P4},
{10,3,11,10,1,3,9,5,4,P7},
{4,9,5,0,8,1,8,10,1,8,11,10,P4},
{5,4,0,5,0,11,5,11,10,11,0,3,P4},
{5,4,8,5,8,10,10,8,11,P7},
{9,7,8,5,7,9,P10},
{9,3,0,9,5,3,5,7,3,P7},
{0,7,8,0,1,7,1,5,7,P7},
{1,5,3,3,5,7,P10},
{9,7,8,9,5,7,10,1,2,P7},
{10,1,2,9,5,0,5,3,0,5,7,3,P4},
{8,0,2,8,2,5,8,5,7,10,5,2,P4},
{2,10,5,2,5,3,3,5,7,P7},
{7,9,5,7,8,9,3,11,2,P7},
{9,5,7,9,7,2,9,2,0,2,7,11,P4},
{2,3,11,0,1,8,1,7,8,1,5,7,P4},
{11,2,1,11,1,7,7,1,5,P7},
{9,5,8,8,5,7,10,1,3,10,3,11,P4},
{5,7,0,5,0,9,7,11,0,1,0,10,11,10,0,P1},
{11,10,0,11,0,3,10,5,0,8,0,7,5,7,0,P1},
{11,10,5,7,11,5,P10},
{10,6,5,P13},
{0,8,3,5,10,6,P10},
{9,0,1,5,10,6,P10},
{1,8,3,1,9,8,5,10,6,P7},
{1,6,5,2,6,1,P10},
{1,6,5,1,2,6,3,0,8,P7},
{9,6,5,9,0,6,0,2,6,P7},
{5,9,8,5,8,2,5,2,6,3,2,8,P4},
{2,3,11,10,6,5,P10},
{11,0,8,11,2,0,10,6,5,P7},
{0,1,9,2,3,11,5,10,6,P7},
{5,10,6,1,9,2,9,11,2,9,8,11,P4},
{6,3,11,6,5,3,5,1,3,P7},
{0,8,11,0,11,5,0,5,1,5,11,6,P4},
{3,11,6,0,3,6,0,6,5,0,5,9,P4},
{6,5,9,6,9,11,11,9,8,P7},
{5,10,6,4,7,8,P10},
{4,3,0,4,7,3,6,5,10,P7},
{1,9,0,5,10,6,8,4,7,P7},
{10,6,5,1,9,7,1,7,3,7,9,4,P4},
{6,1,2,6,5,1,4,7,8,P7},
{1,2,5,5,2,6,3,0,4,3,4,7,P4},
{8,4,7,9,0,5,0,6,5,0,2,6,P4},
{7,3,9,7,9,4,3,2,9,5,9,6,2,6,9,P1},
{3,11,2,7,8,4,10,6,5,P7},
{5,10,6,4,7,2,4,2,0,2,7,11,P4},
{0,1,9,4,7,8,2,3,11,5,10,6,P4},
{9,2,1,9,11,2,9,4,11,7,11,4,5,10,6,P1},
{8,4,7,3,11,5,3,5,1,5,11,6,P4},
{5,1,11,5,11,6,1,0,11,7,11,4,0,4,11,P1},
{0,5,9,0,6,5,0,3,6,11,6,3,8,4,7,P1},
{6,5,9,6,9,11,4,7,9,7,11,9,P4},
{10,4,9,6,4,10,P10},
{4,10,6,4,9,10,0,8,3,P7},
{10,0,1,10,6,0,6,4,0,P7},
{8,3,1,8,1,6,8,6,4,6,1,10,P4},
{1,4,9,1,2,4,2,6,4,P7},
{3,0,8,1,2,9,2,4,9,2,6,4,P4},
{0,2,4,4,2,6,P10},
{8,3,2,8,2,4,4,2,6,P7},
{10,4,9,10,6,4,11,2,3,P7},
{0,8,2,2,8,11,4,9,10,4,10,6,P4},
{3,11,2,0,1,6,0,6,4,6,1,10,P4},
{6,4,1,6,1,10,4,8,1,2,1,11,8,11,1,P1},
{9,6,4,9,3,6,9,1,3,11,6,3,P4},
{8,11,1,8,1,0,11,6,1,9,1,4,6,4,1,P1},
{3,11,6,3,6,0,0,6,4,P7},
{6,4,8,11,6,8,P10},
{7,10,6,7,8,10,8,9,10,P7},
{0,7,3,0,10,7,0,9,10,6,7,10,P4},
{10,6,7,1,10,7,1,7,8,1,8,0,P4},
{10,6,7,10,7,1,1,7,3,P7},
{1,2,6,1,6,8,1,8,9,8,6,7,P4},
{2,6,9,2,9,1,6,7,9,0,9,3,7,3,9,P1},
{7,8,0,7,0,6,6,0,2,P7},
{7,3,2,6,7,2,P10},
{2,3,11,10,6,8,10,8,9,8,6,7,P4},
{2,0,7,2,7,11,0,9,7,6,7,10,9,10,7,P1},
{1,8,0,1,7,8,1,10,7,6,7,10,2,3,11,P1},
{11,2,1,11,1,7,10,6,1,6,7,1,P4},
{8,9,6,8,6,7,9,1,6,11,6,3,1,3,6,P1},
{0,9,1,11,6,7,P10},
{7,8,0,7,0,6,3,11,0,11,6,0,P4},
{7,11,6,P13},
{7,6,11,P13},
{3,0,8,11,7,6,P10},
{0,1,9,11,7,6,P10},
{8,1,9,8,3,1,11,7,6,P7},
{10,1,2,6,11,7,P10},
{1,2,10,3,0,8,6,11,7,P7},
{2,9,0,2,10,9,6,11,7,P7},
{6,11,7,2,10,3,10,8,3,10,9,8,P4},
{7,2,3,6,2,7,P10},
{7,0,8,7,6,0,6,2,0,P7},
{2,7,6,2,3,7,0,1,9,P7},
{1,6,2,1,8,6,1,9,8,8,7,6,P4},
{10,7,6,10,1,7,1,3,7,P7},
{10,7,6,1,7,10,1,8,7,1,0,8,P4},
{0,3,7,0,7,10,0,10,9,6,10,7,P4},
{7,6,10,7,10,8,8,10,9,P7},
{6,8,4,11,8,6,P10},
{3,6,11,3,0,6,0,4,6,P7},
{8,6,11,8,4,6,9,0,1,P7},
{9,4,6,9,6,3,9,3,1,11,3,6,P4},
{6,8,4,6,11,8,2,10,1,P7},
{1,2,10,3,0,11,0,6,11,0,4,6,P4},
{4,11,8,4,6,11,0,2,9,2,10,9,P4},
{10,9,3,10,3,2,9,4,3,11,3,6,4,6,3,P1},
{8,2,3,8,4,2,4,6,2,P7},
{0,4,2,4,6,2,P10},
{1,9,0,2,3,4,2,4,6,4,3,8,P4},
{1,9,4,1,4,2,2,4,6,P7},
{8,1,3,8,6,1,8,4,6,6,10,1,P4},
{10,1,0,10,0,6,6,0,4,P7},
{4,6,3,4,3,8,6,10,3,0,3,9,10,9,3,P1},
{10,9,4,6,10,4,P10},
{4,9,5,7,6,11,P10},
{0,8,3,4,9,5,11,7,6,P7},
{5,0,1,5,4,0,7,6,11,P7},
{11,7,6,8,3,4,3,5,4,3,1,5,P4},
{9,5,4,10,1,2,7,6,11,P7},
{6,11,7,1,2,10,0,8,3,4,9,5,P4},
{7,6,11,5,4,10,4,2,10,4,0,2,P4},
{3,4,8,3,5,4,3,2,5,10,5,2,11,7,6,P1},
{7,2,3,7,6,2,5,4,9,P7},
{9,5,4,0,8,6,0,6,2,6,8,7,P4},
{3,6,2,3,7,6,1,5,0,5,4,0,P4},
{6,2,8,6,8,7,2,1,8,4,8,5,1,5,8,P1},
{9,5,4,10,1,6,1,7,6,1,3,7,P4},
{1,6,10,1,7,6,1,0,7,8,7,0,9,5,4,P1},
{4,0,10,4,10,5,0,3,10,6,10,7,3,7,10,P1},
{7,6,10,7,10,8,5,4,10,4,8,10,P4},
{6,9,5,6,11,9,11,8,9,P7},
{3,6,11,0,6,3,0,5,6,0,9,5,P4},
{0,11,8,0,5,11,0,1,5,5,6,11,P4},
{6,11,3,6,3,5,5,3,1,P7},
{1,2,10,9,5,11,9,11,8,11,5,6,P4},
{0,11,3,0,6,11,0,9,6,5,6,9,1,2,10,P1},
{11,8,5,11,5,6,8,0,5,10,5,2,0,2,5,P1},
{6,11,3,6,3,5,2,10,3,10,5,3,P4},
{5,8,9,5,2,8,5,6,2,3,8,2,P4},
{9,5,6,9,6,0,0,6,2,P7},
{1,5,8,1,8,0,5,6,8,3,8,2,6,2,8,P1},
{1,5,6,2,1,6,P10},
{1,3,6,1,6,10,3,8,6,5,6,9,8,9,6,P1},
{10,1,0,10,0,6,9,5,0,5,6,0,P4},
{0,3,8,5,6,10,P10},
{10,5,6,P13},
{11,5,10,7,5,11,P10},
{11,5,10,11,7,5,8,3,0,P7},
{5,11,7,5,10,11,1,9,0,P7},
{10,7,5,10,11,7,9,8,1,8,3,1,P4},
{11,1,2,11,7,1,7,5,1,P7},
{0,8,3,1,2,7,1,7,5,7,2,11,P4},
{9,7,5,9,2,7,9,0,2,2,11,7,P4},
{7,5,2,7,2,11,5,9,2,3,2,8,9,8,2,P1},
{2,5,10,2,3,5,3,7,5,P7},
{8,2,0,8,5,2,8,7,5,10,2,5,P4},
{9,0,1,5,10,3,5,3,7,3,10,2,P4},
{9,8,2,9,2,1,8,7,2,10,2,5,7,5,2,P1},
{1,3,5,3,7,5,P10},
{0,8,7,0,7,1,1,7,5,P7},
{9,0,3,9,3,5,5,3,7,P7},
{9,8,7,5,9,7,P10},
{5,8,4,5,10,8,10,11,8,P7},
{5,0,4,5,11,0,5,10,11,11,3,0,P4},
{0,1,9,8,4,10,8,10,11,10,4,5,P4},
{10,11,4,10,4,5,11,3,4,9,4,1,3,1,4,P1},
{2,5,1,2,8,5,2,11,8,4,5,8,P4},
{0,4,11,0,11,3,4,5,11,2,11,1,5,1,11,P1},
{0,2,5,0,5,9,2,11,5,4,5,8,11,8,5,P1},
{9,4,5,2,11,3,P10},
{2,5,10,3,5,2,3,4,5,3,8,4,P4},
{5,10,2,5,2,4,4,2,0,P7},
{3,10,2,3,5,10,3,8,5,4,5,8,0,1,9,P1},
{5,10,2,5,2,4,1,9,2,9,4,2,P4},
{8,4,5,8,5,3,3,5,1,P7},
{0,4,5,1,0,5,P10},
{8,4,5,8,5,3,9,0,5,0,3,5,P4},
{9,4,5,P13},
{4,11,7,4,9,11,9,10,11,P7},
{0,8,3,4,9,7,9,11,7,9,10,11,P4},
{1,10,11,1,11,4,1,4,0,7,4,11,P4},
{3,1,4,3,4,8,1,10,4,7,4,11,10,11,4,P1},
{4,11,7,9,11,4,9,2,11,9,1,2,P4},
{9,7,4,9,11,7,9,1,11,2,11,1,0,8,3,P1},
{11,7,4,11,4,2,2,4,0,P7},
{11,7,4,11,4,2,8,3,4,3,2,4,P4},
{2,9,10,2,7,9,2,3,7,7,4,9,P4},
{9,10,7,9,7,4,10,2,7,8,7,0,2,0,7,P1},
{3,7,10,3,10,2,7,4,10,1,10,0,4,0,10,P1},
{1,10,2,8,7,4,P10},
{4,9,1,4,1,7,7,1,3,P7},
{4,9,1,4,1,7,0,8,1,8,7,1,P4},
{4,0,3,7,4,3,P10},
{4,8,7,P13},
{9,10,8,10,11,8,P10},
{3,0,9,3,9,11,11,9,10,P7},
{0,1,10,0,10,8,8,10,11,P7},
{3,1,10,11,3,10,P10},
{1,2,11,1,11,9,9,11,8,P7},
{3,0,9,3,9,11,1,2,9,2,11,9,P4},
{0,2,11,8,0,11,P10},
{3,2,11,P13},
{2,3,8,2,8,10,10,8,9,P7},
{9,10,2,0,9,2,P10},
{2,3,8,2,8,10,0,1,8,1,10,8,P4},
{1,10,2,P13},
{1,3,8,9,1,8,P10},
{0,9,1,P13},
{0,3,8,P13},
{P16}
};

// Packed per-edge corner-offset bits, indexed by edge e in [0,12):
// AX[e]=OX[EA[e]], BX[e]=OX[EB[e]], etc.  (bit 12 = 0, used for invalid slots)
#define MAX_ 0x666
#define MBX_ 0x633
#define MAY_ 0xCCC
#define MBY_ 0xC66
#define MAZ_ 0x0F0
#define MBZ_ 0xFF0

__global__ __launch_bounds__(256) void mc_kernel(const float* __restrict__ vol,
                                                 float* __restrict__ out,
                                                 int* __restrict__ ws) {
    __shared__ __align__(16) float exp_s[256 * 45];    // 46080 B: final layout
    __shared__ unsigned char tvm_s[256];
    __shared__ int wsum[4];

    const int tid = threadIdx.x;
    const long long cell = (long long)blockIdx.x * 256 + tid;
    const bool active = cell < NCELL;

    const int x = (int)(cell % CDIM);
    const int r = (int)(cell / CDIM);
    const int y = r % CDIM;
    const int z = r / CDIM;
    const float xf = (float)x, yf = (float)y, zf = (float)z;

    int4 row = make_int4(-1, -1, -1, -1);
    float tv[12];
#pragma unroll
    for (int e = 0; e < 12; ++e) tv[e] = 0.0f;

    if (active) {
        const float* p = vol + ((size_t)z * DIMV + y) * DIMV + x;
        float cv[8];
        cv[0] = p[0];
        cv[1] = p[1];
        cv[3] = p[DIMV];
        cv[2] = p[DIMV + 1];
        cv[4] = p[DIMV * DIMV];
        cv[5] = p[DIMV * DIMV + 1];
        cv[7] = p[DIMV * DIMV + DIMV];
        cv[6] = p[DIMV * DIMV + DIMV + 1];

        int cidx = 0;
#pragma unroll
        for (int k = 0; k < 8; ++k)
            cidx |= (cv[k] < 0.5f) ? (1 << k) : 0;

        row = ((const int4*)TRI_TBL)[cidx];

        const int EA[12] = {0,1,2,3,4,5,6,7,0,1,2,3};
        const int EB[12] = {1,2,3,0,5,6,7,4,4,5,6,7};
#pragma unroll
        for (int e = 0; e < 12; ++e) {
            const float v1 = cv[EA[e]];
            const float v2 = cv[EB[e]];
            const float d  = v2 - v1;
            tv[e] = (fabsf(d) > 1e-9f) ? ((0.5f - v1) / d) : 0.5f;
        }
    }

    const int rw[4] = {row.x, row.y, row.z, row.w};

    // tri_valid bitmask (bytes 0,3,6,9,12 of the row)
    int m = 0;
#pragma unroll
    for (int t5 = 0; t5 < 5; ++t5) {
        const int b = 3 * t5;
        const int eb = (int)(signed char)((rw[b >> 2] >> ((b & 3) * 8)) & 0xFF);
        m |= (eb >= 0) ? (1 << t5) : 0;
    }
    tvm_s[tid] = (unsigned char)m;
    int cnt = __popc(m);

    // ---- Expansion: own cell's 45 output floats -> exp_s (final layout).
    // t is selected from the 12 registers with a cndmask tree (no LDS).
    // Invalid slots (ec==12) pick a garbage t, but all axis deltas are 0
    // and the result is forced to 0, so it never matters.
    float* ep = &exp_s[tid * 45];
#pragma unroll
    for (int b = 0; b < 15; ++b) {
        const int eb = (int)(signed char)((rw[b >> 2] >> ((b & 3) * 8)) & 0xFF);
        const bool ok = (eb >= 0);
        const int ec = ok ? eb : 12;

        const bool s0 = (ec & 1) != 0;
        const bool s1 = (ec & 2) != 0;
        const bool s2 = (ec & 4) != 0;
        const bool s3 = (ec & 8) != 0;
        const float p0 = s0 ? tv[1]  : tv[0];
        const float p1 = s0 ? tv[3]  : tv[2];
        const float p2 = s0 ? tv[5]  : tv[4];
        const float p3 = s0 ? tv[7]  : tv[6];
        const float p4 = s0 ? tv[9]  : tv[8];
        const float p5 = s0 ? tv[11] : tv[10];
        const float q0 = s1 ? p1 : p0;
        const float q1 = s1 ? p3 : p2;
        const float q2 = s1 ? p5 : p4;
        const float h0 = s2 ? q1 : q0;
        const float t  = s3 ? q2 : h0;

        const int ax = (MAX_ >> ec) & 1, bx = (MBX_ >> ec) & 1;
        const int ay = (MAY_ >> ec) & 1, by = (MBY_ >> ec) & 1;
        const int az = (MAZ_ >> ec) & 1, bz = (MBZ_ >> ec) & 1;
        float vx = (xf + (float)ax) + t * (float)(bx - ax);
        float vy = (yf + (float)ay) + t * (float)(by - ay);
        float vz = (zf + (float)az) + t * (float)(bz - az);
        ep[3*b + 0] = ok ? vx : 0.0f;
        ep[3*b + 1] = ok ? vy : 0.0f;
        ep[3*b + 2] = ok ? vz : 0.0f;
    }

    // ---- Count reduction BEFORE the barrier (no post-store barrier later,
    // so blocks retire with stores still in flight). No atomics: per-block
    // partial into ws; a tiny second kernel does the final sum.
#pragma unroll
    for (int off = 32; off > 0; off >>= 1)
        cnt += __shfl_down(cnt, off);
    if ((tid & 63) == 0) wsum[tid >> 6] = cnt;

    __syncthreads();   // exp_s + tvm_s + wsum all ready

    if (tid == 0)
        ws[blockIdx.x] = wsum[0] + wsum[1] + wsum[2] + wsum[3];

    // ---- Stream LDS -> global (kernel ends with stores in flight) ----
    const size_t base45 = (size_t)blockIdx.x * (256 * 45);
    float4* vout = (float4*)(out + base45);
    const float4* vin = (const float4*)exp_s;

    if (blockIdx.x < FULL_BLOCKS) {
        // 2880 float4s: 11 full rounds + 64-lane tail. Independent copies.
#pragma unroll
        for (int k = 0; k < 11; ++k)
            vout[tid + k * 256] = vin[tid + k * 256];
        if (tid < 64)
            vout[tid + 2816] = vin[tid + 2816];

        float* tvout = out + VTX_FLOATS + (size_t)blockIdx.x * (256 * 5);
#pragma unroll
        for (int k = 0; k < 5; ++k) {
            const int i = tid + k * 256;
            const uint c  = (uint)i / 5u;
            const uint t5 = (uint)i - c * 5u;
            tvout[i] = ((tvm_s[c] >> t5) & 1) ? 1.0f : 0.0f;
        }
    } else {
        // Last block: 127 cells -> 5715 floats = 1428 float4 + 3 tail floats.
        const int nfull4 = 1428;
        for (int i4 = tid; i4 < nfull4; i4 += 256)
            vout[i4] = vin[i4];
        if (tid < 3)
            out[base45 + 5712 + tid] = exp_s[5712 + tid];

        float* tvout = out + VTX_FLOATS + (size_t)blockIdx.x * (256 * 5);
        const int ntv = 127 * 5;
#pragma unroll
        for (int k = 0; k < 3; ++k) {
            const int i = tid + k * 256;
            if (i < ntv) {
                const uint c  = (uint)i / 5u;
                const uint t5 = (uint)i - c * 5u;
                tvout[i] = ((tvm_s[c] >> t5) & 1) ? 1.0f : 0.0f;
            }
        }
    }
}

__global__ __launch_bounds__(1024) void sum_kernel(const int* __restrict__ ws,
                                                   float* __restrict__ out) {
    __shared__ int sh[16];
    const int tid = threadIdx.x;
    int s = 0;
    for (int i = tid; i < NBLK; i += 1024)
        s += ws[i];
#pragma unroll
    for (int off = 32; off > 0; off >>= 1)
        s += __shfl_down(s, off);
    if ((tid & 63) == 0) sh[tid >> 6] = s;
    __syncthreads();
    if (tid == 0) {
        int tot = 0;
#pragma unroll
        for (int k = 0; k < 16; ++k) tot += sh[k];
        out[CNT_OFF] = (float)tot;
    }
}

extern "C" void kernel_launch(void* const* d_in, const int* in_sizes, int n_in,
                              void* d_out, int out_size, void* d_ws, size_t ws_size,
                              hipStream_t stream) {
    const float* vol = (const float*)d_in[0];
    float* out = (float*)d_out;
    int* ws = (int*)d_ws;

    mc_kernel<<<NBLK, 256, 0, stream>>>(vol, out, ws);
    sum_kernel<<<1, 1024, 0, stream>>>(ws, out);
}